// Round 15
// baseline (268.665 us; speedup 1.0000x reference)
//
#include <hip/hip_runtime.h>
#include <stdint.h>

typedef __attribute__((ext_vector_type(4))) float f32x4;
typedef __attribute__((ext_vector_type(8))) short short8;
typedef unsigned short u16;

#define NH 16
#define HD 64
#define SEQ 4096
#define BATCH 4
#define NROWS (BATCH * SEQ)      // 16384
#define DIMC 1024
#define QKVC 3072
#define SCALE 0.125f

__device__ __forceinline__ u16 f2bf(float f) {
  union { float f; uint32_t u; } v; v.f = f;
  uint32_t u = v.u;
  uint32_t r = (u + 0x7fffu + ((u >> 16) & 1u)) >> 16;
  return (u16)r;
}
__device__ __forceinline__ float bf2f(u16 h) {
  union { uint32_t u; float f; } v; v.u = ((uint32_t)h) << 16;
  return v.f;
}

// ---------------- fp32 -> bf16 elementwise convert (grid-stride) ------------
__global__ __launch_bounds__(256) void cvt_kernel(const float* __restrict__ in,
                                                  u16* __restrict__ out, int n4) {
  int stride = gridDim.x * 256;
  for (int i = blockIdx.x * 256 + threadIdx.x; i < n4; i += stride) {
    float4 v = ((const float4*)in)[i];
    ushort4 o;
    o.x = f2bf(v.x); o.y = f2bf(v.y); o.z = f2bf(v.z); o.w = f2bf(v.w);
    ((ushort4*)out)[i] = o;
  }
}

// ------- fp32 [R][C] -> bf16 [C][R] transpose, both weights in one launch ---
__global__ __launch_bounds__(256) void transpose_cvt2(const float* __restrict__ wqkv,
                                                      u16* __restrict__ wqt,
                                                      const float* __restrict__ wout,
                                                      u16* __restrict__ wot) {
  __shared__ float t[32][33];
  const float* in; u16* out; int C, blk;
  if (blockIdx.x < 3072) { in = wqkv; out = wqt; C = 3072; blk = blockIdx.x; }
  else                   { in = wout; out = wot; C = 1024; blk = blockIdx.x - 3072; }
  int R = 1024;
  int nbx = C >> 5;
  int bx = blk % nbx, by = blk / nbx;
  int r0 = by << 5, c0 = bx << 5;
  int tid = threadIdx.x;
#pragma unroll
  for (int i = 0; i < 4; i++) {
    int id = i * 256 + tid; int lr = id >> 5, lc = id & 31;
    t[lr][lc] = in[(size_t)(r0 + lr) * C + (c0 + lc)];
  }
  __syncthreads();
#pragma unroll
  for (int i = 0; i < 4; i++) {
    int id = i * 256 + tid; int lr = id >> 5, lc = id & 31;
    out[(size_t)(c0 + lr) * R + (r0 + lc)] = f2bf(t[lc][lr]);
  }
}

// ---------------- bf16 GEMM: C[M,N] = A[M,K] * Bt[N,K]^T (K=1024) -----------
// Cross-tile A-preload pipeline, register-lean (r13 retry; r13's defect was
// frag spill: WRITE_SIZE +4.6MB). BK=32, 4 LDS buffers (128KiB), NT=32 fixed.
// Per tile t: STAGE(t+2) -> vmcnt(4) [own stage(t+1)] -> barrier [publishes
// stage(t+1) block-wide] -> read b(t) [4 ds] + preload a(t+1) [8 ds, buffer
// (t+1)&3 just published] -> 32 MFMA from a-set preloaded LAST tile. The
// MFMAs' lgkm wait is for old completed reads, so the 12 fresh reads drain
// UNDER the MFMA block: LDS pipe (~2300cy/tile-pair) overlaps MFMA (~2480).
// Frags: aP[2][8] + b[4] = 80 regs (r13 had 96 -> spilled past the hard
// 128-arch budget: 2048 regs/SIMD / 8 waves = 256/wave - 128 acc).
// WAR: buf (t+2)&3 last read at tile t-2, >=2 barriers back. Unroll 4:
// t&3 / (t+1)&1 compile-time (rule #20).
template <int OUT_BF16, int DO_SUMS>
__global__ __launch_bounds__(512, 2) void gemm_bt(const u16* __restrict__ A,
                                                  const u16* __restrict__ Bt,
                                                  void* __restrict__ Cv,
                                                  float* __restrict__ chk,
                                                  float* __restrict__ chv,
                                                  int M, int N, int K) {
  __shared__ __align__(16) u16 lds4[4][16384];   // per buf: A[0..8191], B[8192..16383]
  int nbx = N >> 8;
  int nwg = gridDim.x;
  int bid = blockIdx.x;
  int cpx = nwg >> 3;                       // grids are multiples of 8
  int swz = (bid & 7) * cpx + (bid >> 3);
  int bx = swz % nbx, by = swz / nbx;
  int tid = threadIdx.x, lane = tid & 63, wv = tid >> 6;
  int wr = wv >> 2, wc = wv & 3;            // wave grid 2 (M) x 4 (N)
  int lr = lane & 15, g = lane >> 4;
  int rxk = (g ^ ((lr >> 1) & 3)) << 3;     // read chunk offset (u16 units)
  int rsub4 = lane >> 2;                    // staging: row within 16-row unit
  int clog = (lane & 3) ^ ((lane >> 3) & 3);// staging: logical (global) chunk

  const u16* Ap = A + (size_t)(by * 256) * K;
  const u16* Bp = Bt + (size_t)(bx * 256) * K;

  f32x4 acc[8][4];
#pragma unroll
  for (int m = 0; m < 8; m++)
#pragma unroll
    for (int n = 0; n < 4; n++) acc[m][n] = (f32x4){0.f, 0.f, 0.f, 0.f};

  short8 aP0[8], aP1[8], b[4];              // A double-set + single b set

#define ISSUE_A(L, T) do {                                                      \
    int ru_ = (L) * 128 + wv * 16;                                              \
    const u16* g_ = Ap + (size_t)(ru_ + rsub4) * K + (T) * 32 + clog * 8;       \
    __builtin_amdgcn_global_load_lds(                                           \
        (const __attribute__((address_space(1))) uint32_t*)g_,                  \
        (__attribute__((address_space(3))) uint32_t*)&lds4[(T) & 3][ru_ * 32],  \
        16, 0, 0);                                                              \
  } while (0)

#define ISSUE_B(L, T) do {                                                      \
    int ru_ = (L) * 128 + wv * 16;                                              \
    const u16* g_ = Bp + (size_t)(ru_ + rsub4) * K + (T) * 32 + clog * 8;       \
    __builtin_amdgcn_global_load_lds(                                           \
        (const __attribute__((address_space(1))) uint32_t*)g_,                  \
        (__attribute__((address_space(3)))                                      \
             uint32_t*)&lds4[(T) & 3][8192 + ru_ * 32],                         \
        16, 0, 0);                                                              \
  } while (0)

#define STAGE(T) do { ISSUE_A(0, T); ISSUE_A(1, T); ISSUE_B(0, T); ISSUE_B(1, T); } while (0)

#define LDApre(SA, T) do {                                                      \
    const u16* ab_ = &lds4[(T) & 3][(wr * 128 + lr) * 32 + rxk];                \
    _Pragma("unroll")                                                           \
    for (int m = 0; m < 8; m++) SA[m] = *(const short8*)(ab_ + m * 512);        \
  } while (0)

#define LDBt(T) do {                                                            \
    const u16* bb_ = &lds4[(T) & 3][8192 + (wc * 64 + lr) * 32 + rxk];          \
    _Pragma("unroll")                                                           \
    for (int n = 0; n < 4; n++) b[n] = *(const short8*)(bb_ + n * 512);         \
  } while (0)

  // b-first MFMA order: MFMAs for b[0] wait only b[0] (oldest of the 12
  // outstanding reads) -> short staircase head; a-preload drains under rest.
#define MFMAS(SA) do {                                                          \
    _Pragma("unroll")                                                           \
    for (int n = 0; n < 4; n++)                                                 \
      _Pragma("unroll")                                                         \
      for (int m = 0; m < 8; m++)                                               \
        acc[m][n] = __builtin_amdgcn_mfma_f32_16x16x32_bf16(                    \
            SA[m], b[n], acc[m][n], 0, 0, 0);                                   \
  } while (0)

  // NT = 32 (K = 1024 for both GEMMs)
  // prologue: stage tiles 0,1; retire 0; preload a(0)
  STAGE(0); STAGE(1);
  __builtin_amdgcn_sched_barrier(0);
  asm volatile("s_waitcnt vmcnt(4)" ::: "memory");
  __builtin_amdgcn_s_barrier();
  LDApre(aP0, 0);
  __builtin_amdgcn_sched_barrier(0);

#pragma unroll 4
  for (int t = 0; t < 32; t++) {
    if (t + 2 < 32) STAGE(t + 2);
    __builtin_amdgcn_sched_barrier(0);
    if (t + 2 < 32) asm volatile("s_waitcnt vmcnt(4)" ::: "memory");
    else            asm volatile("s_waitcnt vmcnt(0)" ::: "memory");
    __builtin_amdgcn_s_barrier();
    LDBt(t);
    if (t + 1 < 32) { if ((t & 1) == 0) LDApre(aP1, t + 1); else LDApre(aP0, t + 1); }
    __builtin_amdgcn_sched_barrier(0);
    __builtin_amdgcn_s_setprio(1);
    if ((t & 1) == 0) MFMAS(aP0); else MFMAS(aP1);
    __builtin_amdgcn_s_setprio(0);
    __builtin_amdgcn_sched_barrier(0);
  }

#undef ISSUE_A
#undef ISSUE_B
#undef STAGE
#undef LDApre
#undef LDBt
#undef MFMAS

  int rb = by * 256 + wr * 128, cb = bx * 256 + wc * 64;

  if (DO_SUMS && cb >= 1024) {
    // fused chunk means: wave owns chunks (wr*2+mh); sum fp32 acc over rows.
#pragma unroll
    for (int mh = 0; mh < 2; mh++)
#pragma unroll
      for (int n = 0; n < 4; n++) {
        float sum = 0.f;
#pragma unroll
        for (int m = mh * 4; m < mh * 4 + 4; m++)
#pragma unroll
          for (int r = 0; r < 4; r++) sum += acc[m][n][r];
        sum += __shfl_xor(sum, 16);
        sum += __shfl_xor(sum, 32);
        if (g == 0) {
          int grb = rb + mh * 64;
          int b_ = grb >> 12, c = (grb >> 6) & 63;
          int cg = cb + n * 16 + lr;
          int col = cg & 1023;
          int h = col >> 6, d = col & 63;
          float* dst = (cg < 2048) ? chk : chv;
          dst[(((size_t)(b_ * 16 + h)) * 64 + c) * 64 + d] = sum * 0.015625f;
        }
      }
  }

#pragma unroll
  for (int m = 0; m < 8; m++)
#pragma unroll
    for (int n = 0; n < 4; n++)
#pragma unroll
      for (int r = 0; r < 4; r++) {
        int rg = rb + m * 16 + g * 4 + r;
        int cg = cb + n * 16 + lr;
        float v = acc[m][n][r];
        if (OUT_BF16)
          ((u16*)Cv)[(size_t)rg * N + cg] = f2bf(v);
        else
          ((float*)Cv)[(size_t)rg * N + cg] = v;
      }
}

// ---------------- exclusive cumsum over chunks (4-way split scan) ----------
__global__ __launch_bounds__(256) void cumsum_excl(const float* __restrict__ ck,
                                                   const float* __restrict__ cv,
                                                   float* __restrict__ cuk,
                                                   float* __restrict__ cuv) {
  __shared__ float qk[4][64], qv[4][64];
  int bh = blockIdx.x;                       // 64 blocks (b*16+h)
  int d = threadIdx.x & 63, q = threadIdx.x >> 6;
  size_t base = ((size_t)bh * 64) * 64 + d;
  float sk = 0.f, sv = 0.f;
  for (int c = q * 16; c < q * 16 + 16; c++) {
    sk += ck[base + (size_t)c * 64];
    sv += cv[base + (size_t)c * 64];
  }
  qk[q][d] = sk; qv[q][d] = sv;
  __syncthreads();
  float ak = 0.f, av = 0.f;
  for (int p = 0; p < q; p++) { ak += qk[p][d]; av += qv[p][d]; }
  for (int c = q * 16; c < q * 16 + 16; c++) {
    size_t i = base + (size_t)c * 64;
    cuk[i] = ak; cuv[i] = av;
    ak += ck[i]; av += cv[i];
  }
}

// ---------------- per-chunk attention + cross term ----------------
// 34 KB LDS (4 blocks/CU): p_s overlays q_s (warp-private rows, DS in-order).
// vt_s chunk-XOR swizzle (write col (r&7)|(((r>>3)^qt)<<3); read col
// kt*32+((g^n)<<3)).
__global__ __launch_bounds__(256) void attn_kernel(const u16* __restrict__ qkv,
                                                   const float* __restrict__ cuk,
                                                   const float* __restrict__ cuv,
                                                   u16* __restrict__ out) {
  int blk = blockIdx.x;
  int c = blk & 63, h = (blk >> 6) & 15, b = blk >> 10;
  int row0 = b * SEQ + c * 64;
  __shared__ u16 qp_s[64][88];   // Q during QK^T, then P for PV
  __shared__ u16 k_s[64][88];
  __shared__ u16 vt_s[64][88];   // V transposed + chunk-XOR swizzled
  __shared__ u16 ck_s[64];
  __shared__ float cv_s[64];
  int tid = threadIdx.x;
  {
    if (tid < 64) {
      ck_s[tid] = f2bf(cuk[(size_t)blk * 64 + tid]);
      cv_s[tid] = cuv[(size_t)blk * 64 + tid];
    }
    int r = tid >> 2, qt = tid & 3;
    const u16* rp = qkv + (size_t)(row0 + r) * QKVC + h * 64 + qt * 16;
    uint4 q0 = *(const uint4*)rp;          uint4 q1 = *(const uint4*)(rp + 8);
    uint4 k0 = *(const uint4*)(rp + 1024); uint4 k1 = *(const uint4*)(rp + 1032);
    uint4 v0 = *(const uint4*)(rp + 2048); uint4 v1 = *(const uint4*)(rp + 2056);
    *(uint4*)&qp_s[r][qt * 16] = q0;    *(uint4*)&qp_s[r][qt * 16 + 8] = q1;
    *(uint4*)&k_s[r][qt * 16] = k0;     *(uint4*)&k_s[r][qt * 16 + 8] = k1;
    const u16* vv0 = (const u16*)&v0;   const u16* vv1 = (const u16*)&v1;
    int vcol = (r & 7) | ((((r >> 3) ^ qt) & 7) << 3);
#pragma unroll
    for (int j = 0; j < 8; j++) vt_s[qt * 16 + j][vcol] = vv0[j];
#pragma unroll
    for (int j = 0; j < 8; j++) vt_s[qt * 16 + 8 + j][vcol] = vv1[j];
  }
  __syncthreads();

  int lane = tid & 63, w = tid >> 6;
  int lr = lane & 15, g = lane >> 4;
  f32x4 accS[4];
#pragma unroll
  for (int n = 0; n < 4; n++) accS[n] = (f32x4){0.f, 0.f, 0.f, 0.f};
  f32x4 accC = (f32x4){0.f, 0.f, 0.f, 0.f};
  short8 zf = (short8){0, 0, 0, 0, 0, 0, 0, 0};
#pragma unroll
  for (int kt = 0; kt < 2; kt++) {
    int lk = kt * 32 + g * 8;
    short8 af = *(const short8*)&qp_s[w * 16 + lr][lk];
    short8 cf = (lr == 0) ? *(const short8*)&ck_s[lk] : zf;
    accC = __builtin_amdgcn_mfma_f32_16x16x32_bf16(af, cf, accC, 0, 0, 0);
#pragma unroll
    for (int n = 0; n < 4; n++) {
      short8 bf = *(const short8*)&k_s[n * 16 + lr][lk];
      accS[n] = __builtin_amdgcn_mfma_f32_16x16x32_bf16(af, bf, accS[n], 0, 0, 0);
    }
  }
  float crossv[4];
#pragma unroll
  for (int r4 = 0; r4 < 4; r4++) {
    int row = w * 16 + g * 4 + r4;
    float x[4];
    float mx = -3.4e38f;
#pragma unroll
    for (int n = 0; n < 4; n++) {
      int col = n * 16 + lr;
      x[n] = ((col & 63) > (row & 63)) ? -65000.0f : accS[n][r4] * SCALE;
      mx = fmaxf(mx, x[n]);
    }
    mx = fmaxf(mx, __shfl_xor(mx, 1));
    mx = fmaxf(mx, __shfl_xor(mx, 2));
    mx = fmaxf(mx, __shfl_xor(mx, 4));
    mx = fmaxf(mx, __shfl_xor(mx, 8));
    float p[4], sum = 0.f;
#pragma unroll
    for (int n = 0; n < 4; n++) { p[n] = __expf(x[n] - mx); sum += p[n]; }
    sum += __shfl_xor(sum, 1);
    sum += __shfl_xor(sum, 2);
    sum += __shfl_xor(sum, 4);
    sum += __shfl_xor(sum, 8);
    float inv = 1.0f / sum;
#pragma unroll
    for (int n = 0; n < 4; n++) qp_s[row][n * 16 + lr] = f2bf(p[n] * inv);
    float sg = 1.0f / (1.0f + __expf(-accC[r4] * SCALE));
    crossv[r4] = __shfl(sg, (lane & 48));
  }
  __syncthreads();
  f32x4 accO[4];
#pragma unroll
  for (int n = 0; n < 4; n++) accO[n] = (f32x4){0.f, 0.f, 0.f, 0.f};
#pragma unroll
  for (int kt = 0; kt < 2; kt++) {
    int lk = kt * 32 + g * 8;
    short8 pf = *(const short8*)&qp_s[w * 16 + lr][lk];
#pragma unroll
    for (int n = 0; n < 4; n++) {
      short8 vf = *(const short8*)&vt_s[n * 16 + lr][kt * 32 + ((g ^ n) << 3)];
      accO[n] = __builtin_amdgcn_mfma_f32_16x16x32_bf16(pf, vf, accO[n], 0, 0, 0);
    }
  }
#pragma unroll
  for (int n = 0; n < 4; n++)
#pragma unroll
    for (int r4 = 0; r4 < 4; r4++) {
      int row = w * 16 + g * 4 + r4;
      int col = n * 16 + lr;
      float v = accO[n][r4] + crossv[r4] * cv_s[col] * 0.5f;
      out[(size_t)(row0 + row) * DIMC + h * 64 + col] = f2bf(v);
    }
}

extern "C" void kernel_launch(void* const* d_in, const int* in_sizes, int n_in,
                              void* d_out, int out_size, void* d_ws, size_t ws_size,
                              hipStream_t stream) {
  const float* x = (const float*)d_in[0];
  const float* Wqkv = (const float*)d_in[1];
  const float* Wout = (const float*)d_in[2];
  char* ws = (char*)d_ws;
  size_t off = 0;
  auto alloc = [&](size_t b) {
    void* p = ws + off;
    off += (b + 255) & ~(size_t)255;
    return p;
  };
  u16* xb = (u16*)alloc((size_t)NROWS * DIMC * 2);        // 32MB, reused as attnb
  u16* wqt = (u16*)alloc((size_t)QKVC * DIMC * 2);        // 6MB
  u16* wot = (u16*)alloc((size_t)DIMC * DIMC * 2);        // 2MB
  u16* qkvb = (u16*)alloc((size_t)NROWS * QKVC * 2);      // 96MB
  float* chk = (float*)alloc((size_t)4096 * 64 * 4);
  float* chv = (float*)alloc((size_t)4096 * 64 * 4);
  float* cuk = (float*)alloc((size_t)4096 * 64 * 4);
  float* cuv = (float*)alloc((size_t)4096 * 64 * 4);
  u16* attnb = xb;

  cvt_kernel<<<2048, 256, 0, stream>>>(x, xb, NROWS * DIMC / 4);
  transpose_cvt2<<<4096, 256, 0, stream>>>(Wqkv, wqt, Wout, wot);
  gemm_bt<1, 1><<<768, 512, 0, stream>>>(xb, wqt, qkvb, chk, chv, NROWS, QKVC, DIMC);
  cumsum_excl<<<64, 256, 0, stream>>>(chk, chv, cuk, cuv);
  attn_kernel<<<4096, 256, 0, stream>>>(qkvb, cuk, cuv, attnb);
  gemm_bt<0, 0><<<256, 512, 0, stream>>>(attnb, wot, d_out, nullptr, nullptr,
                                         NROWS, DIMC, DIMC);
}

// Round 16
// 192.392 us; speedup vs baseline: 1.3964x; 1.3964x over previous
//
#include <hip/hip_runtime.h>
#include <stdint.h>

typedef __attribute__((ext_vector_type(4))) float f32x4;
typedef __attribute__((ext_vector_type(8))) short short8;
typedef unsigned short u16;

#define NH 16
#define HD 64
#define SEQ 4096
#define BATCH 4
#define NROWS (BATCH * SEQ)      // 16384
#define DIMC 1024
#define QKVC 3072
#define SCALE 0.125f

__device__ __forceinline__ u16 f2bf(float f) {
  union { float f; uint32_t u; } v; v.f = f;
  uint32_t u = v.u;
  uint32_t r = (u + 0x7fffu + ((u >> 16) & 1u)) >> 16;
  return (u16)r;
}
__device__ __forceinline__ float bf2f(u16 h) {
  union { uint32_t u; float f; } v; v.u = ((uint32_t)h) << 16;
  return v.f;
}

// ---------------- fp32 -> bf16 elementwise convert (grid-stride) ------------
__global__ __launch_bounds__(256) void cvt_kernel(const float* __restrict__ in,
                                                  u16* __restrict__ out, int n4) {
  int stride = gridDim.x * 256;
  for (int i = blockIdx.x * 256 + threadIdx.x; i < n4; i += stride) {
    float4 v = ((const float4*)in)[i];
    ushort4 o;
    o.x = f2bf(v.x); o.y = f2bf(v.y); o.z = f2bf(v.z); o.w = f2bf(v.w);
    ((ushort4*)out)[i] = o;
  }
}

// ------- fp32 [R][C] -> bf16 [C][R] transpose, both weights in one launch ---
// blocks [0, 3072): Wqkv (R=1024, C=3072); blocks [3072, 4096): Wout (1024^2).
__global__ __launch_bounds__(256) void transpose_cvt2(const float* __restrict__ wqkv,
                                                      u16* __restrict__ wqt,
                                                      const float* __restrict__ wout,
                                                      u16* __restrict__ wot) {
  __shared__ float t[32][33];
  const float* in; u16* out; int C, blk;
  if (blockIdx.x < 3072) { in = wqkv; out = wqt; C = 3072; blk = blockIdx.x; }
  else                   { in = wout; out = wot; C = 1024; blk = blockIdx.x - 3072; }
  int R = 1024;
  int nbx = C >> 5;
  int bx = blk % nbx, by = blk / nbx;
  int r0 = by << 5, c0 = bx << 5;
  int tid = threadIdx.x;
#pragma unroll
  for (int i = 0; i < 4; i++) {
    int id = i * 256 + tid; int lr = id >> 5, lc = id & 31;
    t[lr][lc] = in[(size_t)(r0 + lr) * C + (c0 + lc)];
  }
  __syncthreads();
#pragma unroll
  for (int i = 0; i < 4; i++) {
    int id = i * 256 + tid; int lr = id >> 5, lc = id & 31;
    out[(size_t)(c0 + lr) * R + (r0 + lc)] = f2bf(t[lc][lr]);
  }
}

// ---------------- bf16 GEMM: C[M,N] = A[M,K] * Bt[N,K]^T ----------------
// Round-6/11/12/14 structure (best measured: ~105us QKV, MfmaUtil ~42%, 0
// bank conflicts, no spill). BM=BN=256, BK=64, 512 thr = 8 waves (2M x 4N),
// per-wave 128x64 (acc[8][4], 16x16x32 MFMA). LDS 128 KiB = 2 dbuf.
// One barrier per K-tile; reads grouped ahead of MFMA staircase; compiler
// inserts counted lgkm waits so tail reads drain under MFMA. FROZEN:
// r7-r15 tested 7 deeper-pipeline variants (8-phase x3, cross-tile BK=32 x2,
// 32x32 shape, 1-barrier groupings) -- none beat this. Register file caps
// the CU at 8 waves (128 acc + 128 arch VGPR each); schedules needing more
// live arch regs spill (r7/r13/r15: WRITE_SIZE +4.6..+32MB), schedules that
// fit land at the same ~42% LDS/MFMA-serialized plateau.
template <int OUT_BF16, int DO_SUMS>
__global__ __launch_bounds__(512, 2) void gemm_bt(const u16* __restrict__ A,
                                                  const u16* __restrict__ Bt,
                                                  void* __restrict__ Cv,
                                                  float* __restrict__ chk,
                                                  float* __restrict__ chv,
                                                  int M, int N, int K) {
  __shared__ __align__(16) u16 lds2[2][32768];   // per dbuf: A[0..16383], B[16384..32767]
  int nbx = N >> 8;
  int nwg = gridDim.x;
  int bid = blockIdx.x;
  int cpx = nwg >> 3;                       // grids are multiples of 8
  int swz = (bid & 7) * cpx + (bid >> 3);
  int bx = swz % nbx, by = swz / nbx;
  int tid = threadIdx.x, lane = tid & 63, wv = tid >> 6;
  int wr = wv >> 2, wc = wv & 3;            // wave grid 2 (M) x 4 (N)
  int lr = lane & 15, g = lane >> 4;
  int rx = lr & 7;
  int rsub = lane >> 3;                     // staging: row within 8-row unit
  int clog = (lane & 7) ^ rsub;             // staging: logical (global) chunk

  const u16* Ap = A + (size_t)(by * 256) * K;
  const u16* Bp = Bt + (size_t)(bx * 256) * K;

  f32x4 acc[8][4];
#pragma unroll
  for (int m = 0; m < 8; m++)
#pragma unroll
    for (int n = 0; n < 4; n++) acc[m][n] = (f32x4){0.f, 0.f, 0.f, 0.f};

  short8 a0[4][2], a1[4][2], b0[2][2], b1[2][2];

#define ISSUE_A(HALF, L, T) do {                                                \
    int ru_ = (HALF) * 128 + (L) * 64 + wv * 8;                                 \
    const u16* g_ = Ap + (size_t)(ru_ + rsub) * K + (T) * 64 + clog * 8;        \
    __builtin_amdgcn_global_load_lds(                                           \
        (const __attribute__((address_space(1))) uint32_t*)g_,                  \
        (__attribute__((address_space(3))) uint32_t*)&lds2[(T) & 1][ru_ * 64],  \
        16, 0, 0);                                                              \
  } while (0)

#define ISSUE_B(HALF, L, T) do {                                                \
    int ru_ = (HALF) * 128 + (L) * 64 + wv * 8;                                 \
    const u16* g_ = Bp + (size_t)(ru_ + rsub) * K + (T) * 64 + clog * 8;        \
    __builtin_amdgcn_global_load_lds(                                           \
        (const __attribute__((address_space(1))) uint32_t*)g_,                  \
        (__attribute__((address_space(3)))                                      \
             uint32_t*)&lds2[(T) & 1][16384 + ru_ * 64],                        \
        16, 0, 0);                                                              \
  } while (0)

#define LDA4(DST, MH, T) do {                                                   \
    _Pragma("unroll")                                                           \
    for (int m2 = 0; m2 < 4; m2++) {                                            \
      int row_ = wr * 128 + ((MH) * 4 + m2) * 16 + lr;                          \
      const u16* bp_ = &lds2[(T) & 1][row_ * 64];                               \
      _Pragma("unroll")                                                         \
      for (int s = 0; s < 2; s++)                                               \
        DST[m2][s] = *(const short8*)(bp_ + (((s * 4 + g) ^ rx) << 3));         \
    }                                                                           \
  } while (0)

#define LDB(DST, NHh, T) do {                                                   \
    _Pragma("unroll")                                                           \
    for (int n2 = 0; n2 < 2; n2++) {                                            \
      int row_ = wc * 64 + ((NHh) * 2 + n2) * 16 + lr;                          \
      const u16* bp_ = &lds2[(T) & 1][16384 + row_ * 64];                       \
      _Pragma("unroll")                                                         \
      for (int s = 0; s < 2; s++)                                               \
        DST[n2][s] = *(const short8*)(bp_ + (((s * 4 + g) ^ rx) << 3));         \
    }                                                                           \
  } while (0)

#define MFMA_Q(MH, NHh, AA, BB) do {                                            \
    _Pragma("unroll")                                                           \
    for (int s = 0; s < 2; s++)                                                 \
      _Pragma("unroll")                                                         \
      for (int m2 = 0; m2 < 4; m2++)                                            \
        _Pragma("unroll")                                                       \
        for (int n2 = 0; n2 < 2; n2++)                                          \
          acc[(MH) * 4 + m2][(NHh) * 2 + n2] =                                  \
              __builtin_amdgcn_mfma_f32_16x16x32_bf16(                          \
                  AA[m2][s], BB[n2][s], acc[(MH) * 4 + m2][(NHh) * 2 + n2],     \
                  0, 0, 0);                                                     \
  } while (0)

  int NT = K >> 6;
  // prologue: stage tile 0 into buf0, drain
  ISSUE_A(0, 0, 0); ISSUE_A(0, 1, 0); ISSUE_A(1, 0, 0); ISSUE_A(1, 1, 0);
  ISSUE_B(0, 0, 0); ISSUE_B(0, 1, 0); ISSUE_B(1, 0, 0); ISSUE_B(1, 1, 0);
  __syncthreads();

  for (int t = 0; t < NT; t++) {
    // group 1: frags for Q00
    LDA4(a0, 0, t);
    LDB(b0, 0, t);
    __builtin_amdgcn_sched_barrier(0);
    // stage A of tile t+1 (other buffer; prior readers retired at last barrier)
    if (t + 1 < NT) {
      ISSUE_A(0, 0, t + 1); ISSUE_A(0, 1, t + 1);
      ISSUE_A(1, 0, t + 1); ISSUE_A(1, 1, t + 1);
    }
    __builtin_amdgcn_sched_barrier(0);
    // group 2: remaining frags
    LDB(b1, 1, t);
    LDA4(a1, 1, t);
    __builtin_amdgcn_sched_barrier(0);
    // stage B of tile t+1
    if (t + 1 < NT) {
      ISSUE_B(0, 0, t + 1); ISSUE_B(0, 1, t + 1);
      ISSUE_B(1, 0, t + 1); ISSUE_B(1, 1, t + 1);
    }
    __builtin_amdgcn_sched_barrier(0);
    // MFMA staircase: compiler-counted lgkm waits
    __builtin_amdgcn_s_setprio(1);
    MFMA_Q(0, 0, a0, b0);
    __builtin_amdgcn_sched_barrier(0);
    MFMA_Q(0, 1, a0, b1);
    __builtin_amdgcn_sched_barrier(0);
    MFMA_Q(1, 1, a1, b1);
    __builtin_amdgcn_sched_barrier(0);
    MFMA_Q(1, 0, a1, b0);
    __builtin_amdgcn_s_setprio(0);
    __syncthreads();   // drains own vmcnt (stages) + lgkm; one barrier per tile
  }

#undef ISSUE_A
#undef ISSUE_B
#undef LDA4
#undef LDB
#undef MFMA_Q

  int rb = by * 256 + wr * 128, cb = bx * 256 + wc * 64;

  if (DO_SUMS && cb >= 1024) {
    // fused chunk means: wave owns chunks (wr*2+mh); sum fp32 acc over rows.
#pragma unroll
    for (int mh = 0; mh < 2; mh++)
#pragma unroll
      for (int n = 0; n < 4; n++) {
        float sum = 0.f;
#pragma unroll
        for (int m = mh * 4; m < mh * 4 + 4; m++)
#pragma unroll
          for (int r = 0; r < 4; r++) sum += acc[m][n][r];
        sum += __shfl_xor(sum, 16);
        sum += __shfl_xor(sum, 32);
        if (g == 0) {
          int grb = rb + mh * 64;
          int b = grb >> 12, c = (grb >> 6) & 63;
          int cg = cb + n * 16 + lr;
          int col = cg & 1023;
          int h = col >> 6, d = col & 63;
          float* dst = (cg < 2048) ? chk : chv;
          dst[(((size_t)(b * 16 + h)) * 64 + c) * 64 + d] = sum * 0.015625f;
        }
      }
  }

#pragma unroll
  for (int m = 0; m < 8; m++)
#pragma unroll
    for (int n = 0; n < 4; n++)
#pragma unroll
      for (int r = 0; r < 4; r++) {
        int rg = rb + m * 16 + g * 4 + r;
        int cg = cb + n * 16 + lr;
        float v = acc[m][n][r];
        if (OUT_BF16)
          ((u16*)Cv)[(size_t)rg * N + cg] = f2bf(v);
        else
          ((float*)Cv)[(size_t)rg * N + cg] = v;
      }
}

// ---------------- exclusive cumsum over chunks (4-way split scan) ----------
__global__ __launch_bounds__(256) void cumsum_excl(const float* __restrict__ ck,
                                                   const float* __restrict__ cv,
                                                   float* __restrict__ cuk,
                                                   float* __restrict__ cuv) {
  __shared__ float qk[4][64], qv[4][64];
  int bh = blockIdx.x;                       // 64 blocks (b*16+h)
  int d = threadIdx.x & 63, q = threadIdx.x >> 6;
  size_t base = ((size_t)bh * 64) * 64 + d;
  float sk = 0.f, sv = 0.f;
  for (int c = q * 16; c < q * 16 + 16; c++) {
    sk += ck[base + (size_t)c * 64];
    sv += cv[base + (size_t)c * 64];
  }
  qk[q][d] = sk; qv[q][d] = sv;
  __syncthreads();
  float ak = 0.f, av = 0.f;
  for (int p = 0; p < q; p++) { ak += qk[p][d]; av += qv[p][d]; }
  for (int c = q * 16; c < q * 16 + 16; c++) {
    size_t i = base + (size_t)c * 64;
    cuk[i] = ak; cuv[i] = av;
    ak += ck[i]; av += cv[i];
  }
}

// ---------------- per-chunk attention + cross term ----------------
// 34 KB LDS (4 blocks/CU): p_s overlays q_s (warp-private rows, DS in-order).
// vt_s chunk-XOR swizzle (write col (r&7)|(((r>>3)^qt)<<3); read col
// kt*32+((g^n)<<3)).
__global__ __launch_bounds__(256) void attn_kernel(const u16* __restrict__ qkv,
                                                   const float* __restrict__ cuk,
                                                   const float* __restrict__ cuv,
                                                   u16* __restrict__ out) {
  int blk = blockIdx.x;
  int c = blk & 63, h = (blk >> 6) & 15, b = blk >> 10;
  int row0 = b * SEQ + c * 64;
  __shared__ u16 qp_s[64][88];   // Q during QK^T, then P for PV
  __shared__ u16 k_s[64][88];
  __shared__ u16 vt_s[64][88];   // V transposed + chunk-XOR swizzled
  __shared__ u16 ck_s[64];
  __shared__ float cv_s[64];
  int tid = threadIdx.x;
  {
    if (tid < 64) {
      ck_s[tid] = f2bf(cuk[(size_t)blk * 64 + tid]);
      cv_s[tid] = cuv[(size_t)blk * 64 + tid];
    }
    int r = tid >> 2, qt = tid & 3;
    const u16* rp = qkv + (size_t)(row0 + r) * QKVC + h * 64 + qt * 16;
    uint4 q0 = *(const uint4*)rp;          uint4 q1 = *(const uint4*)(rp + 8);
    uint4 k0 = *(const uint4*)(rp + 1024); uint4 k1 = *(const uint4*)(rp + 1032);
    uint4 v0 = *(const uint4*)(rp + 2048); uint4 v1 = *(const uint4*)(rp + 2056);
    *(uint4*)&qp_s[r][qt * 16] = q0;    *(uint4*)&qp_s[r][qt * 16 + 8] = q1;
    *(uint4*)&k_s[r][qt * 16] = k0;     *(uint4*)&k_s[r][qt * 16 + 8] = k1;
    const u16* vv0 = (const u16*)&v0;   const u16* vv1 = (const u16*)&v1;
    int vcol = (r & 7) | ((((r >> 3) ^ qt) & 7) << 3);
#pragma unroll
    for (int j = 0; j < 8; j++) vt_s[qt * 16 + j][vcol] = vv0[j];
#pragma unroll
    for (int j = 0; j < 8; j++) vt_s[qt * 16 + 8 + j][vcol] = vv1[j];
  }
  __syncthreads();

  int lane = tid & 63, w = tid >> 6;
  int lr = lane & 15, g = lane >> 4;
  f32x4 accS[4];
#pragma unroll
  for (int n = 0; n < 4; n++) accS[n] = (f32x4){0.f, 0.f, 0.f, 0.f};
  f32x4 accC = (f32x4){0.f, 0.f, 0.f, 0.f};
  short8 zf = (short8){0, 0, 0, 0, 0, 0, 0, 0};
#pragma unroll
  for (int kt = 0; kt < 2; kt++) {
    int lk = kt * 32 + g * 8;
    short8 af = *(const short8*)&qp_s[w * 16 + lr][lk];
    short8 cf = (lr == 0) ? *(const short8*)&ck_s[lk] : zf;
    accC = __builtin_amdgcn_mfma_f32_16x16x32_bf16(af, cf, accC, 0, 0, 0);
#pragma unroll
    for (int n = 0; n < 4; n++) {
      short8 bf = *(const short8*)&k_s[n * 16 + lr][lk];
      accS[n] = __builtin_amdgcn_mfma_f32_16x16x32_bf16(af, bf, accS[n], 0, 0, 0);
    }
  }
  float crossv[4];
#pragma unroll
  for (int r4 = 0; r4 < 4; r4++) {
    int row = w * 16 + g * 4 + r4;
    float x[4];
    float mx = -3.4e38f;
#pragma unroll
    for (int n = 0; n < 4; n++) {
      int col = n * 16 + lr;
      x[n] = ((col & 63) > (row & 63)) ? -65000.0f : accS[n][r4] * SCALE;
      mx = fmaxf(mx, x[n]);
    }
    mx = fmaxf(mx, __shfl_xor(mx, 1));
    mx = fmaxf(mx, __shfl_xor(mx, 2));
    mx = fmaxf(mx, __shfl_xor(mx, 4));
    mx = fmaxf(mx, __shfl_xor(mx, 8));
    float p[4], sum = 0.f;
#pragma unroll
    for (int n = 0; n < 4; n++) { p[n] = __expf(x[n] - mx); sum += p[n]; }
    sum += __shfl_xor(sum, 1);
    sum += __shfl_xor(sum, 2);
    sum += __shfl_xor(sum, 4);
    sum += __shfl_xor(sum, 8);
    float inv = 1.0f / sum;
#pragma unroll
    for (int n = 0; n < 4; n++) qp_s[row][n * 16 + lr] = f2bf(p[n] * inv);
    float sg = 1.0f / (1.0f + __expf(-accC[r4] * SCALE));
    crossv[r4] = __shfl(sg, (lane & 48));
  }
  __syncthreads();
  f32x4 accO[4];
#pragma unroll
  for (int n = 0; n < 4; n++) accO[n] = (f32x4){0.f, 0.f, 0.f, 0.f};
#pragma unroll
  for (int kt = 0; kt < 2; kt++) {
    int lk = kt * 32 + g * 8;
    short8 pf = *(const short8*)&qp_s[w * 16 + lr][lk];
#pragma unroll
    for (int n = 0; n < 4; n++) {
      short8 vf = *(const short8*)&vt_s[n * 16 + lr][kt * 32 + ((g ^ n) << 3)];
      accO[n] = __builtin_amdgcn_mfma_f32_16x16x32_bf16(pf, vf, accO[n], 0, 0, 0);
    }
  }
#pragma unroll
  for (int n = 0; n < 4; n++)
#pragma unroll
    for (int r4 = 0; r4 < 4; r4++) {
      int row = w * 16 + g * 4 + r4;
      int col = n * 16 + lr;
      float v = accO[n][r4] + crossv[r4] * cv_s[col] * 0.5f;
      out[(size_t)(row0 + row) * DIMC + h * 64 + col] = f2bf(v);
    }
}

extern "C" void kernel_launch(void* const* d_in, const int* in_sizes, int n_in,
                              void* d_out, int out_size, void* d_ws, size_t ws_size,
                              hipStream_t stream) {
  const float* x = (const float*)d_in[0];
  const float* Wqkv = (const float*)d_in[1];
  const float* Wout = (const float*)d_in[2];
  char* ws = (char*)d_ws;
  size_t off = 0;
  auto alloc = [&](size_t b) {
    void* p = ws + off;
    off += (b + 255) & ~(size_t)255;
    return p;
  };
  u16* xb = (u16*)alloc((size_t)NROWS * DIMC * 2);        // 32MB, reused as attnb
  u16* wqt = (u16*)alloc((size_t)QKVC * DIMC * 2);        // 6MB
  u16* wot = (u16*)alloc((size_t)DIMC * DIMC * 2);        // 2MB
  u16* qkvb = (u16*)alloc((size_t)NROWS * QKVC * 2);      // 96MB
  float* chk = (float*)alloc((size_t)4096 * 64 * 4);
  float* chv = (float*)alloc((size_t)4096 * 64 * 4);
  float* cuk = (float*)alloc((size_t)4096 * 64 * 4);
  float* cuv = (float*)alloc((size_t)4096 * 64 * 4);
  u16* attnb = xb;

  cvt_kernel<<<2048, 256, 0, stream>>>(x, xb, NROWS * DIMC / 4);
  transpose_cvt2<<<4096, 256, 0, stream>>>(Wqkv, wqt, Wout, wot);
  gemm_bt<1, 1><<<768, 512, 0, stream>>>(xb, wqt, qkvb, chk, chv, NROWS, QKVC, DIMC);
  cumsum_excl<<<64, 256, 0, stream>>>(chk, chv, cuk, cuv);
  attn_kernel<<<4096, 256, 0, stream>>>(qkvb, cuk, cuv, attnb);
  gemm_bt<0, 0><<<256, 512, 0, stream>>>(attnb, wot, d_out, nullptr, nullptr,
                                         NROWS, DIMC, DIMC);
}